// Round 4
// baseline (174.243 us; speedup 1.0000x reference)
//
#include <hip/hip_runtime.h>

#define NEG 5
#define MM 6             // morphemes per word
#define NCTX 6           // 1 + NEG
#define NC 36            // ctx morphemes per row
#define DD 128
#define WPB 2            // waves per block, 1 batch row per wave
#define DROW 12          // data row stride
#define ROW_F 128        // floats per staged row
#define NINST 21         // global_load_lds per row: 18 ctx + 3 word
#define WAVE_LDS_F (NINST * 256)   // 5376 floats = 21504 B
#define WORD_OFF (NC * ROW_F)      // word rows after 36 ctx rows
#define NSLOT 1024

__device__ __forceinline__ void gload_lds16(const float* g, const float* l) {
    __builtin_amdgcn_global_load_lds(
        (const __attribute__((address_space(1))) unsigned int*)g,
        (__attribute__((address_space(3))) unsigned int*)(uintptr_t)l,
        16, 0, 0);
}

__global__ __launch_bounds__(WPB * 64) void sg_gather_kernel(
    const int*   __restrict__ data,       // [B, 12]
    const int*   __restrict__ w2m,        // [B, 6]
    const float* __restrict__ w2m_mask,   // [B, 6]
    const int*   __restrict__ c2m,        // [B, 36]
    const float* __restrict__ c2m_mask,   // [B, 36]
    const float* __restrict__ emb0,       // [V, 128]
    const float* __restrict__ emb1,       // [V, 128]
    float*       __restrict__ ws,
    int B)
{
    __shared__ float smem[WPB * WAVE_LDS_F];
    const int lane = threadIdx.x & 63;
    const int wid  = __builtin_amdgcn_readfirstlane(threadIdx.x >> 6);
    const int b    = blockIdx.x * WPB + wid;       // wave-uniform row
    float* L = smem + wid * WAVE_LDS_F;

    if (b < B) {
        // ---- wave-uniform (scalar) index & mask loads ----
        int ci[NC]; float cmf[NC];
        #pragma unroll
        for (int t = 0; t < NC; ++t) {
            ci[t]  = c2m[(size_t)b * NC + t];
            cmf[t] = c2m_mask[(size_t)b * NC + t];
        }
        int wi[MM]; float wmf[MM];
        #pragma unroll
        for (int m = 0; m < MM; ++m) {
            wi[m]  = w2m[(size_t)b * MM + m];
            wmf[m] = w2m_mask[(size_t)b * MM + m];
        }
        float nmf[NEG];
        #pragma unroll
        for (int n = 0; n < NEG; ++n)
            nmf[n] = (float)data[(size_t)b * DROW + 2 + NEG + n];

        const int hs = lane >> 5;      // half-wave: which of the 2 rows this instr covers
        const int sl = lane & 31;      // 16B chunk within the row

        // ---- stage: 18 ctx-row instrs + 3 word-row instrs, all async to LDS ----
        #pragma unroll
        for (int k = 0; k < 18; ++k) {
            const int idx = hs ? ci[2 * k + 1] : ci[2 * k];
            gload_lds16(emb1 + (size_t)idx * DD + sl * 4, L + k * 256);
        }
        #pragma unroll
        for (int k = 0; k < 3; ++k) {
            const int idx = hs ? wi[2 * k + 1] : wi[2 * k];
            gload_lds16(emb0 + (size_t)idx * DD + sl * 4, L + WORD_OFF + k * 256);
        }

        asm volatile("s_waitcnt vmcnt(0)" ::: "memory");

        // ---- consume from LDS: lane owns dims d0, d0+1 ----
        const int d0 = lane * 2;

        float wx = 0.0f, wy = 0.0f;
        #pragma unroll
        for (int m = 0; m < MM; ++m) {
            const float2 r = *reinterpret_cast<const float2*>(&L[WORD_OFF + m * ROW_F + d0]);
            wx += r.x * wmf[m];
            wy += r.y * wmf[m];
        }

        float p[NCTX];
        #pragma unroll
        for (int j = 0; j < NCTX; ++j) {
            float ex = 0.0f, ey = 0.0f;
            #pragma unroll
            for (int m = 0; m < MM; ++m) {
                const int t = j * MM + m;
                const float2 r = *reinterpret_cast<const float2*>(&L[t * ROW_F + d0]);
                ex += r.x * cmf[t];
                ey += r.y * cmf[t];
            }
            p[j] = wx * ex + wy * ey;
        }

        // ---- wave butterfly reduce of the 6 dots ----
        #pragma unroll
        for (int j = 0; j < NCTX; ++j) {
            float v = p[j];
            #pragma unroll
            for (int off = 32; off >= 1; off >>= 1)
                v += __shfl_xor(v, off, 64);
            p[j] = v;
        }

        if (lane == 0) {
            float x = fminf(fmaxf(p[0], -10.0f), 10.0f);
            float loss = log1pf(expf(-x));
            #pragma unroll
            for (int n = 0; n < NEG; ++n) {
                float y = fminf(fmaxf(-p[1 + n], -10.0f), 10.0f);
                loss += log1pf(expf(-y)) * nmf[n];
            }
            atomicAdd(&ws[blockIdx.x & (NSLOT - 1)], loss);
        }
    }
}

__global__ __launch_bounds__(256) void sg_reduce_kernel(
    const float* __restrict__ ws, float* __restrict__ out)
{
    const int t = threadIdx.x;
    float s = ws[t] + ws[t + 256] + ws[t + 512] + ws[t + 768];
    #pragma unroll
    for (int off = 32; off >= 1; off >>= 1)
        s += __shfl_xor(s, off, 64);
    __shared__ float a[4];
    if ((t & 63) == 0) a[t >> 6] = s;
    __syncthreads();
    if (t == 0) out[0] = a[0] + a[1] + a[2] + a[3];
}

extern "C" void kernel_launch(void* const* d_in, const int* in_sizes, int n_in,
                              void* d_out, int out_size, void* d_ws, size_t ws_size,
                              hipStream_t stream) {
    const int*   data     = (const int*)  d_in[0];
    const int*   w2m      = (const int*)  d_in[1];
    const float* w2m_mask = (const float*)d_in[2];
    const int*   c2m      = (const int*)  d_in[3];
    const float* c2m_mask = (const float*)d_in[4];
    const float* emb0     = (const float*)d_in[5];
    const float* emb1     = (const float*)d_in[6];
    float* out = (float*)d_out;
    float* ws  = (float*)d_ws;

    const int B = in_sizes[1] / MM;   // word2morph has B*6 elements

    hipMemsetAsync(ws, 0, NSLOT * sizeof(float), stream);

    const int blocks = (B + WPB - 1) / WPB;
    sg_gather_kernel<<<blocks, WPB * 64, 0, stream>>>(
        data, w2m, w2m_mask, c2m, c2m_mask, emb0, emb1, ws, B);
    sg_reduce_kernel<<<1, 256, 0, stream>>>(ws, out);
}

// Round 5
// 109.893 us; speedup vs baseline: 1.5856x; 1.5856x over previous
//
#include <hip/hip_runtime.h>

#define NEG 5
#define MM 6            // morphemes per word
#define NCTX 6          // 1 + NEG
#define DD 128
#define WPB 4           // waves per block
#define RPW 2           // rows per wave (one half-wave = one row)
#define RPB (WPB * RPW) // 8 rows per block
#define DROW 12         // data row stride = 2 + 2*NEG

#define SB() __builtin_amdgcn_sched_barrier(0)

__device__ __forceinline__ int geti(const int4& v, int c) {
    switch (c) { case 0: return v.x; case 1: return v.y; case 2: return v.z; default: return v.w; }
}
__device__ __forceinline__ float getf(const float4& v, int c) {
    switch (c) { case 0: return v.x; case 1: return v.y; case 2: return v.z; default: return v.w; }
}

// issue the 6 gathers for context J into dst[0..5]
template<int J>
__device__ __forceinline__ void issue_ctx(float4* dst, const int4& ci, int base,
                                          const float* __restrict__ emb1, int d0) {
    #pragma unroll
    for (int m = 0; m < MM; ++m) {
        const int flat = J * MM + m;          // compile-time after unroll
        const int k = flat >> 2, c = flat & 3;
        const int idx = __shfl(geti(ci, c), base + k, 64);
        dst[m] = *reinterpret_cast<const float4*>(emb1 + (size_t)idx * DD + d0);
    }
}

// consume context J: masked bag-sum then dot with w
template<int J>
__device__ __forceinline__ float consume_ctx(const float4* src, const float4& cmk,
                                             int base, const float4& w) {
    float ex = 0.f, ey = 0.f, ez = 0.f, ew = 0.f;
    #pragma unroll
    for (int m = 0; m < MM; ++m) {
        const int flat = J * MM + m;
        const int k = flat >> 2, c = flat & 3;
        const float mk = __shfl(getf(cmk, c), base + 9 + k, 64);
        ex += src[m].x * mk; ey += src[m].y * mk;
        ez += src[m].z * mk; ew += src[m].w * mk;
    }
    return w.x * ex + w.y * ey + w.z * ez + w.w * ew;
}

__global__ __launch_bounds__(256) void sg_loss_kernel(
    const int*   __restrict__ data,           // [B, 12]
    const int*   __restrict__ w2m,            // [B, 6]
    const float* __restrict__ w2m_mask,       // [B, 6]
    const int*   __restrict__ c2m,            // [B, 36]
    const float* __restrict__ c2m_mask,       // [B, 36]
    const float* __restrict__ emb0,           // [V, 128]
    const float* __restrict__ emb1,           // [V, 128]
    float*       __restrict__ out,
    int B)
{
    const int lane  = threadIdx.x & 63;
    const int wid   = threadIdx.x >> 6;
    const int sub   = lane >> 5;
    const int slane = lane & 31;
    const int base  = lane & 32;        // shuffle base for this half-wave
    const int b     = blockIdx.x * RPB + wid * RPW + sub;

    float loss = 0.0f;

    if (b < B) {
        // ---------- lane-parallel prefetch of all indices/masks ----------
        int4   ci  = {0, 0, 0, 0};          // lanes 0..8  : ctx indices (9 x int4)
        float4 cmk = {0.f, 0.f, 0.f, 0.f};  // lanes 9..17 : ctx masks   (9 x float4)
        int    wi  = 0;                     // lanes 18..23: word indices
        float  wmk = 0.f;                   // lanes 24..29: word masks
        int    nm  = 0;                     // lanes 0..4  : negative masks

        if (slane < 9) {
            ci  = reinterpret_cast<const int4*>(c2m + (size_t)b * (NCTX * MM))[slane];
        } else if (slane < 18) {
            cmk = reinterpret_cast<const float4*>(c2m_mask + (size_t)b * (NCTX * MM))[slane - 9];
        } else if (slane < 24) {
            wi  = w2m[(size_t)b * MM + (slane - 18)];
        } else if (slane < 30) {
            wmk = w2m_mask[(size_t)b * MM + (slane - 24)];
        }
        if (slane < NEG) nm = data[(size_t)b * DROW + 2 + NEG + slane];

        float nmf[NEG];
        #pragma unroll
        for (int n = 0; n < NEG; ++n)
            nmf[n] = (float)__shfl(nm, base + n, 64);

        const int d0 = slane * 4;

        // ---------- software pipeline: W, C0, C1 issued up front ----------
        float4 wr[MM];
        #pragma unroll
        for (int m = 0; m < MM; ++m) {
            const int idx = __shfl(wi, base + 18 + m, 64);
            wr[m] = *reinterpret_cast<const float4*>(emb0 + (size_t)idx * DD + d0);
        }
        float4 A[MM], Bv[MM], C[MM];
        issue_ctx<0>(A,  ci, base, emb1, d0);
        issue_ctx<1>(Bv, ci, base, emb1, d0);
        SB();

        // consume word bag (oldest loads) while C0/C1 are in flight
        float4 w = {0.f, 0.f, 0.f, 0.f};
        #pragma unroll
        for (int m = 0; m < MM; ++m) {
            const float mk = __shfl(wmk, base + 24 + m, 64);
            w.x += wr[m].x * mk; w.y += wr[m].y * mk;
            w.z += wr[m].z * mk; w.w += wr[m].w * mk;
        }
        issue_ctx<2>(C, ci, base, emb1, d0);
        SB();

        float p[NCTX];
        p[0] = consume_ctx<0>(A,  cmk, base, w);  issue_ctx<3>(A,  ci, base, emb1, d0); SB();
        p[1] = consume_ctx<1>(Bv, cmk, base, w);  issue_ctx<4>(Bv, ci, base, emb1, d0); SB();
        p[2] = consume_ctx<2>(C,  cmk, base, w);  issue_ctx<5>(C,  ci, base, emb1, d0); SB();
        p[3] = consume_ctx<3>(A,  cmk, base, w);
        p[4] = consume_ctx<4>(Bv, cmk, base, w);
        p[5] = consume_ctx<5>(C,  cmk, base, w);

        // ---------- per-half-wave (32-lane) butterfly reduction of 6 dots ----------
        #pragma unroll
        for (int j = 0; j < NCTX; ++j) {
            float v = p[j];
            #pragma unroll
            for (int off = 16; off >= 1; off >>= 1)
                v += __shfl_xor(v, off, 64);
            p[j] = v;
        }

        if (slane == 0) {
            float x = fminf(fmaxf(p[0], -10.0f), 10.0f);
            loss = log1pf(expf(-x));
            #pragma unroll
            for (int n = 0; n < NEG; ++n) {
                float y = fminf(fmaxf(-p[1 + n], -10.0f), 10.0f);
                loss += log1pf(expf(-y)) * nmf[n];
            }
        }
    }

    // ---------- block reduce: 8 partials -> 1 atomic ----------
    __shared__ float sacc[RPB];
    if (slane == 0) sacc[wid * RPW + sub] = loss;
    __syncthreads();
    if (threadIdx.x == 0) {
        float s = 0.0f;
        #pragma unroll
        for (int i = 0; i < RPB; ++i) s += sacc[i];
        atomicAdd(out, s);
    }
}

extern "C" void kernel_launch(void* const* d_in, const int* in_sizes, int n_in,
                              void* d_out, int out_size, void* d_ws, size_t ws_size,
                              hipStream_t stream) {
    const int*   data     = (const int*)  d_in[0];
    const int*   w2m      = (const int*)  d_in[1];
    const float* w2m_mask = (const float*)d_in[2];
    const int*   c2m      = (const int*)  d_in[3];
    const float* c2m_mask = (const float*)d_in[4];
    const float* emb0     = (const float*)d_in[5];
    const float* emb1     = (const float*)d_in[6];
    float* out = (float*)d_out;

    const int B = in_sizes[1] / MM;   // word2morph has B*6 elements

    hipMemsetAsync(out, 0, sizeof(float), stream);

    const int blocks = (B + RPB - 1) / RPB;
    sg_loss_kernel<<<blocks, 64 * WPB, 0, stream>>>(
        data, w2m, w2m_mask, c2m, c2m_mask, emb0, emb1, out, B);
}